// Round 8
// baseline (224.555 us; speedup 1.0000x reference)
//
#include <hip/hip_runtime.h>

typedef __attribute__((ext_vector_type(8))) unsigned short ushort8v;
typedef __attribute__((ext_vector_type(8))) short short8v;
typedef __attribute__((ext_vector_type(4))) float f32x4;

__device__ inline unsigned short f2bf(float f) {
    union { float f; unsigned u; } v; v.f = f;
    unsigned u = v.u;
    unsigned r = (u + 0x7FFFu + ((u >> 16) & 1u)) >> 16;
    return (unsigned short)r;
}
__device__ inline float bf2f(unsigned short h) {
    union { unsigned u; float f; } v; v.u = ((unsigned)h) << 16;
    return v.f;
}

#define CAP 64  // bucket capacity; deg ~ Poisson(16), P(deg>=64) ~ 1e-21

// ---------------------------------------------------------------------------
// Fused pre-pass: feat->bf16 (X2 cols 128..255) + weight prep.
// ---------------------------------------------------------------------------
__global__ __launch_bounds__(256) void fused_pre(
    const float* __restrict__ feat, unsigned short* __restrict__ X2, int totalF,
    const float* __restrict__ W1, const float* __restrict__ W2,
    const float* __restrict__ LW,
    unsigned short* __restrict__ W1t, unsigned short* __restrict__ W3t,
    int cvtB) {
    int b = blockIdx.x, t = threadIdx.x;
    if (b < cvtB) {
        int idx = (b * 256 + t) * 4;
        if (idx >= totalF) return;
        float4 v = *(const float4*)(feat + idx);
        int row = idx >> 7, col = idx & 127;
        unsigned short* o = X2 + (size_t)row * 256 + 128 + col;
        *(ushort4*)o = make_ushort4(f2bf(v.x), f2bf(v.y), f2bf(v.z), f2bf(v.w));
    } else {
        int i = (b - cvtB) * 256 + t;  // 0..65535
        if (i < 32768) {
            int jj = i >> 7, k = i & 127;
            float v = (jj < 128) ? W1[k * 128 + jj] : W1[(128 + k) * 128 + (jj - 128)];
            W1t[i] = f2bf(v);
        } else {
            int i2 = i - 32768;
            int n = i2 >> 8, k = i2 & 255;
            float v = (k < 128) ? W2[k * 128 + n] : LW[(k - 128) * 128 + n];
            W3t[i2] = f2bf(v);
        }
    }
}

// ---------------------------------------------------------------------------
// GEMM tile, BK=64 staging (32 KB LDS -> ~5 blocks/CU), used by gemm1.
// ---------------------------------------------------------------------------
__device__ void gemm_tile_bf16out(
    unsigned short* As, unsigned short* Bs,   // each 128 x 64
    const unsigned short* __restrict__ A, int lda,
    const unsigned short* __restrict__ Bt, int ldb, int nRowsB,
    unsigned short* __restrict__ Cout, int ldc,
    int M, int K, int m0, int n0) {
    const int tid = threadIdx.x;
    const int lane = tid & 63;
    const int w = tid >> 6;
    const int wr = w >> 1, wc = w & 1;
    const int q = lane >> 4, ln = lane & 15;

    f32x4 acc[4][4];
#pragma unroll
    for (int i = 0; i < 4; i++)
#pragma unroll
        for (int j = 0; j < 4; j++) acc[i][j] = (f32x4)0.f;

    for (int kk = 0; kk < K; kk += 64) {
#pragma unroll
        for (int i = 0; i < 4; i++) {   // stage A 128x64
            int id = i * 256 + tid;
            int r = id >> 3, b = id & 7;
            ushort8v v = (ushort8v)(unsigned short)0;
            int gr = m0 + r;
            if (gr < M) v = *(const ushort8v*)(A + (size_t)gr * lda + kk + b * 8);
            *(ushort8v*)(As + r * 64 + ((b ^ (r & 7)) * 8)) = v;
        }
#pragma unroll
        for (int i = 0; i < 4; i++) {   // stage B 128x64
            int id = i * 256 + tid;
            int r = id >> 3, b = id & 7;
            ushort8v v = (ushort8v)(unsigned short)0;
            int gr = n0 + r;
            if (gr < nRowsB) v = *(const ushort8v*)(Bt + (size_t)gr * ldb + kk + b * 8);
            *(ushort8v*)(Bs + r * 64 + ((b ^ (r & 7)) * 8)) = v;
        }
        __syncthreads();
#pragma unroll
        for (int ks = 0; ks < 2; ks++) {
            short8v af[4], bfv[4];
#pragma unroll
            for (int ti = 0; ti < 4; ti++) {
                int m = wr * 64 + ti * 16 + ln;
                int blk = (ks * 4 + q) ^ (m & 7);
                af[ti] = *(const short8v*)(As + m * 64 + blk * 8);
            }
#pragma unroll
            for (int tj = 0; tj < 4; tj++) {
                int n = wc * 64 + tj * 16 + ln;
                int blk = (ks * 4 + q) ^ (n & 7);
                bfv[tj] = *(const short8v*)(Bs + n * 64 + blk * 8);
            }
#pragma unroll
            for (int ti = 0; ti < 4; ti++)
#pragma unroll
                for (int tj = 0; tj < 4; tj++)
                    acc[ti][tj] = __builtin_amdgcn_mfma_f32_16x16x32_bf16(
                        af[ti], bfv[tj], acc[ti][tj], 0, 0, 0);
        }
        __syncthreads();
    }

#pragma unroll
    for (int ti = 0; ti < 4; ti++) {
        int rowb = m0 + wr * 64 + ti * 16 + q * 4;
#pragma unroll
        for (int tj = 0; tj < 4; tj++) {
            int col = n0 + wc * 64 + tj * 16 + ln;
            f32x4 c = acc[ti][tj];
#pragma unroll
            for (int r = 0; r < 4; r++) {
                int row = rowb + r;
                if (row < M) Cout[(size_t)row * ldc + col] = f2bf(c[r]);
            }
        }
    }
}

// ---------------------------------------------------------------------------
// Fused gemm1 + bucket-scatter, interleaved by blockIdx&1. u32 payloads
// (u16 stores regressed the TCC atomic/write pipe in round 7).
// ---------------------------------------------------------------------------
__global__ __launch_bounds__(256) void gemm1_scatter(
    const unsigned short* __restrict__ X2feat, const unsigned short* __restrict__ W1t,
    unsigned short* __restrict__ AB,
    const int* __restrict__ src, const int* __restrict__ dst,
    int* __restrict__ cur, int* __restrict__ eSrc,
    int E, int gemmB, int N) {
    __shared__ unsigned short smem[2 * 128 * 64];
    int b = blockIdx.x;
    int half = b >> 1;
    if ((b & 1) == 0) {
        if (half >= gemmB) return;
        int m0 = (half >> 1) * 128, n0 = (half & 1) * 128;
        gemm_tile_bf16out(smem, smem + 128 * 64, X2feat, 256, W1t, 128, 256,
                          AB, 256, N, 128, m0, n0);
    } else {
        int e = (half * 256 + threadIdx.x) * 4;
        if (e + 3 < E) {
            int4 s4 = *(const int4*)(src + e);
            int4 d4 = *(const int4*)(dst + e);
            int p0 = atomicAdd(&cur[d4.x], 1);
            int p1 = atomicAdd(&cur[d4.y], 1);
            int p2 = atomicAdd(&cur[d4.z], 1);
            int p3 = atomicAdd(&cur[d4.w], 1);
            eSrc[(size_t)d4.x * CAP + min(p0, CAP - 1)] = s4.x;
            eSrc[(size_t)d4.y * CAP + min(p1, CAP - 1)] = s4.y;
            eSrc[(size_t)d4.z * CAP + min(p2, CAP - 1)] = s4.z;
            eSrc[(size_t)d4.w * CAP + min(p3, CAP - 1)] = s4.w;
        } else {
            for (int i = e; i < E && i >= 0; i++) {
                int d = dst[i];
                int pos = atomicAdd(&cur[d], 1);
                eSrc[(size_t)d * CAP + min(pos, CAP - 1)] = src[i];
            }
        }
    }
}

// ---------------------------------------------------------------------------
// Fused gather + gemm2. Block b owns rows [m0, m0+128):
//   Phase 1: each wave gathers 32 rows -> S' bf16 into Sg (128x128, 16-block
//            XOR swizzle = A-fragment layout).
//   Phase 2: out[m0.., 0..127] = [S' | feat] @ W3t^T + bias, K=256.
//            kk2=0,1: A-frags read directly from Sg.
//            kk2=2,3: A (feat half) staged from global into As == Sg[0..16K)
//            (alias safe: all Sg reads complete before kk2=2 staging).
// LDS = Sg 32K + Bs 16K = 48 KB -> 3 blocks/CU (12 waves for latency hiding).
// ---------------------------------------------------------------------------
__global__ __launch_bounds__(256) void gather_gemm2(
    const unsigned short* __restrict__ AB, const int* __restrict__ cur,
    const int* __restrict__ eSrc, const unsigned short* __restrict__ X2feat,
    const unsigned short* __restrict__ W3t, const float* __restrict__ bias,
    float* __restrict__ out, int N) {
    __shared__ unsigned short Sg[128 * 128];
    __shared__ unsigned short Bs[128 * 64];
    const int tid = threadIdx.x;
    const int lane = tid & 63;
    const int w = tid >> 6;
    const int m0 = blockIdx.x * 128;
    const int half = lane >> 5, ln32 = lane & 31;

    // ---- Phase 1: gather 32 rows per wave into Sg ----
    for (int rr = w; rr < 128; rr += 4) {
        int row = m0 + rr;
        int kb = ln32 >> 1;                       // 8-elem block 0..15
        int sgoff = rr * 128 + ((kb ^ (rr & 15)) * 8) + (ln32 & 1) * 4;
        if (row >= N) {
            if (half == 0) *(ushort4*)(Sg + sgoff) = make_ushort4(0, 0, 0, 0);
            continue;
        }
        int num = min(cur[row], CAP);
        size_t start = (size_t)row * CAP;
        ushort4 bv = *(const ushort4*)(AB + (size_t)row * 256 + 128 + ln32 * 4);
        float b0 = bf2f(bv.x), b1 = bf2f(bv.y), b2 = bf2f(bv.z), b3 = bf2f(bv.w);
        float p0 = 0.f, p1 = 0.f, p2 = 0.f, p3 = 0.f;
        int mySrc = (lane < num) ? eSrc[start + lane] : 0;
        int j = 0;
        for (; j + 8 <= num; j += 8) {
            ushort4 v[4];
#pragma unroll
            for (int u = 0; u < 4; u++) {
                int s = __shfl(mySrc, j + 2 * u + half);
                v[u] = *(const ushort4*)(AB + (size_t)s * 256 + ln32 * 4);
            }
#pragma unroll
            for (int u = 0; u < 4; u++) {
                p0 += fmaxf(bf2f(v[u].x) + b0, 0.f);
                p1 += fmaxf(bf2f(v[u].y) + b1, 0.f);
                p2 += fmaxf(bf2f(v[u].z) + b2, 0.f);
                p3 += fmaxf(bf2f(v[u].w) + b3, 0.f);
            }
        }
        for (; j < num; j += 2) {
            int idx = j + half;
            int s = __shfl(mySrc, idx);
            bool ok = idx < num;
            ushort4 v = *(const ushort4*)(AB + (size_t)s * 256 + ln32 * 4);
            float m = ok ? 1.f : 0.f;
            p0 += m * fmaxf(bf2f(v.x) + b0, 0.f);
            p1 += m * fmaxf(bf2f(v.y) + b1, 0.f);
            p2 += m * fmaxf(bf2f(v.z) + b2, 0.f);
            p3 += m * fmaxf(bf2f(v.w) + b3, 0.f);
        }
        p0 += __shfl_xor(p0, 32);
        p1 += __shfl_xor(p1, 32);
        p2 += __shfl_xor(p2, 32);
        p3 += __shfl_xor(p3, 32);
        if (half == 0)
            *(ushort4*)(Sg + sgoff) = make_ushort4(f2bf(p0), f2bf(p1), f2bf(p2), f2bf(p3));
    }
    __syncthreads();

    // ---- Phase 2: GEMM, K=256 ----
    const int wr = w >> 1, wc = w & 1;
    const int q = lane >> 4, ln = lane & 15;
    f32x4 acc[4][4];
#pragma unroll
    for (int i = 0; i < 4; i++)
#pragma unroll
        for (int j = 0; j < 4; j++) acc[i][j] = (f32x4)0.f;

    unsigned short* As = Sg;  // alias: feat-half staging reuses Sg[0..16K)
    for (int kk2 = 0; kk2 < 4; kk2++) {
        int kk = kk2 * 64;
        if (kk2 >= 2) {
#pragma unroll
            for (int i = 0; i < 4; i++) {   // stage feat half 128x64
                int id = i * 256 + tid;
                int r = id >> 3, b = id & 7;
                ushort8v v = (ushort8v)(unsigned short)0;
                int gr = m0 + r;
                if (gr < N)
                    v = *(const ushort8v*)(X2feat + (size_t)gr * 256 + (kk - 128) + b * 8);
                *(ushort8v*)(As + r * 64 + ((b ^ (r & 7)) * 8)) = v;
            }
        }
#pragma unroll
        for (int i = 0; i < 4; i++) {   // stage W3t 128x64
            int id = i * 256 + tid;
            int r = id >> 3, b = id & 7;
            ushort8v v = *(const ushort8v*)(W3t + (size_t)r * 256 + kk + b * 8);
            *(ushort8v*)(Bs + r * 64 + ((b ^ (r & 7)) * 8)) = v;
        }
        __syncthreads();
#pragma unroll
        for (int ks = 0; ks < 2; ks++) {
            short8v af[4], bfv[4];
#pragma unroll
            for (int ti = 0; ti < 4; ti++) {
                int m = wr * 64 + ti * 16 + ln;
                if (kk2 < 2) {
                    int blk = (kk2 * 8 + ks * 4 + q) ^ (m & 15);
                    af[ti] = *(const short8v*)(Sg + m * 128 + blk * 8);
                } else {
                    int blk = (ks * 4 + q) ^ (m & 7);
                    af[ti] = *(const short8v*)(As + m * 64 + blk * 8);
                }
            }
#pragma unroll
            for (int tj = 0; tj < 4; tj++) {
                int n = wc * 64 + tj * 16 + ln;
                int blk = (ks * 4 + q) ^ (n & 7);
                bfv[tj] = *(const short8v*)(Bs + n * 64 + blk * 8);
            }
#pragma unroll
            for (int ti = 0; ti < 4; ti++)
#pragma unroll
                for (int tj = 0; tj < 4; tj++)
                    acc[ti][tj] = __builtin_amdgcn_mfma_f32_16x16x32_bf16(
                        af[ti], bfv[tj], acc[ti][tj], 0, 0, 0);
        }
        __syncthreads();
    }

#pragma unroll
    for (int ti = 0; ti < 4; ti++) {
        int rowb = m0 + wr * 64 + ti * 16 + q * 4;
#pragma unroll
        for (int tj = 0; tj < 4; tj++) {
            int col = wc * 64 + tj * 16 + ln;
            f32x4 c = acc[ti][tj];
            float bv = bias[col];
#pragma unroll
            for (int r = 0; r < 4; r++) {
                int row = rowb + r;
                if (row < N) out[(size_t)row * 128 + col] = c[r] + bv;
            }
        }
    }
}

// ---------------------------------------------------------------------------
extern "C" void kernel_launch(void* const* d_in, const int* in_sizes, int n_in,
                              void* d_out, int out_size, void* d_ws, size_t ws_size,
                              hipStream_t stream) {
    const float* feat = (const float*)d_in[0];
    const int* src = (const int*)d_in[1];
    const int* dst = (const int*)d_in[2];
    const float* W1 = (const float*)d_in[3];
    const float* W2 = (const float*)d_in[4];
    const float* LW = (const float*)d_in[5];
    const float* bias = (const float*)d_in[6];
    float* out = (float*)d_out;

    const int N = in_sizes[0] / 128;  // 50000
    const int E = in_sizes[1];        // 800000

    char* ws = (char*)d_ws;
    unsigned short* X2 = (unsigned short*)ws;            // [N,256] bf16: 128-255=feat
    size_t off_b = (size_t)N * 256 * 2;
    unsigned short* AB = (unsigned short*)(ws + off_b);  // [N,256] bf16: A | B
    off_b += (size_t)N * 256 * 2;
    unsigned short* W1t = (unsigned short*)(ws + off_b);
    off_b += (size_t)256 * 128 * 2;
    unsigned short* W3t = (unsigned short*)(ws + off_b);
    off_b += (size_t)128 * 256 * 2;
    int* cur = (int*)(ws + off_b);   off_b += (size_t)N * 4;
    int* eSrc = (int*)(ws + off_b);  off_b += (size_t)N * CAP * 4;  // 12.8 MB

    int totalF = N * 128;
    int cvtB = (totalF / 4 + 255) / 256;

    hipMemsetAsync(cur, 0, (size_t)N * 4, stream);
    fused_pre<<<cvtB + 256, 256, 0, stream>>>(
        feat, X2, totalF, W1, W2, LW, W1t, W3t, cvtB);

    int gemmB = ((N + 127) / 128) * 2;     // 782 gemm tiles
    int scatB = ((E + 3) / 4 + 255) / 256; // 782 scatter chunks
    int mx = gemmB > scatB ? gemmB : scatB;
    gemm1_scatter<<<2 * mx, 256, 0, stream>>>(
        X2 + 128, W1t, AB, src, dst, cur, eSrc, E, gemmB, N);

    gather_gemm2<<<(N + 127) / 128, 256, 0, stream>>>(
        AB, cur, eSrc, X2 + 128, W3t, bias, out, N);
}

// Round 9
// 183.658 us; speedup vs baseline: 1.2227x; 1.2227x over previous
//
#include <hip/hip_runtime.h>

typedef __attribute__((ext_vector_type(8))) unsigned short ushort8v;
typedef __attribute__((ext_vector_type(8))) short short8v;
typedef __attribute__((ext_vector_type(4))) float f32x4;

__device__ inline unsigned short f2bf(float f) {
    union { float f; unsigned u; } v; v.f = f;
    unsigned u = v.u;
    unsigned r = (u + 0x7FFFu + ((u >> 16) & 1u)) >> 16;
    return (unsigned short)r;
}
__device__ inline float bf2f(unsigned short h) {
    union { unsigned u; float f; } v; v.u = ((unsigned)h) << 16;
    return v.f;
}

#define CAP 64  // bucket capacity; deg ~ Poisson(16), P(deg>=64) ~ 1e-21

// ---------------------------------------------------------------------------
// Fused pre-pass: feat->bf16 (X2 cols 128..255) + weight prep.
// ---------------------------------------------------------------------------
__global__ __launch_bounds__(256) void fused_pre(
    const float* __restrict__ feat, unsigned short* __restrict__ X2, int totalF,
    const float* __restrict__ W1, const float* __restrict__ W2,
    const float* __restrict__ LW,
    unsigned short* __restrict__ W1t, unsigned short* __restrict__ W3t,
    int cvtB) {
    int b = blockIdx.x, t = threadIdx.x;
    if (b < cvtB) {
        int idx = (b * 256 + t) * 4;
        if (idx >= totalF) return;
        float4 v = *(const float4*)(feat + idx);
        int row = idx >> 7, col = idx & 127;
        unsigned short* o = X2 + (size_t)row * 256 + 128 + col;
        *(ushort4*)o = make_ushort4(f2bf(v.x), f2bf(v.y), f2bf(v.z), f2bf(v.w));
    } else {
        int i = (b - cvtB) * 256 + t;  // 0..65535
        if (i < 32768) {
            int jj = i >> 7, k = i & 127;
            float v = (jj < 128) ? W1[k * 128 + jj] : W1[(128 + k) * 128 + (jj - 128)];
            W1t[i] = f2bf(v);
        } else {
            int i2 = i - 32768;
            int n = i2 >> 8, k = i2 & 255;
            float v = (k < 128) ? W2[k * 128 + n] : LW[(k - 128) * 128 + n];
            W3t[i2] = f2bf(v);
        }
    }
}

// ---------------------------------------------------------------------------
// GEMM tile, BK=64 staging (32 KB LDS -> ~5 blocks/CU).
// XOR swizzle over 8x 16B blocks per 64-wide row; 2-way LDS aliasing (free).
// ---------------------------------------------------------------------------
template <bool OUT_BF16>
__device__ void gemm_tile(
    unsigned short* As, unsigned short* Bs,   // each 128 x 64
    const unsigned short* __restrict__ A, int lda,
    const unsigned short* __restrict__ Bt, int ldb, int nRowsB,
    void* __restrict__ Cout, int ldc,
    const float* __restrict__ bias, int M, int K, int m0, int n0) {
    const int tid = threadIdx.x;
    const int lane = tid & 63;
    const int w = tid >> 6;
    const int wr = w >> 1, wc = w & 1;
    const int q = lane >> 4, ln = lane & 15;

    f32x4 acc[4][4];
#pragma unroll
    for (int i = 0; i < 4; i++)
#pragma unroll
        for (int j = 0; j < 4; j++) acc[i][j] = (f32x4)0.f;

    for (int kk = 0; kk < K; kk += 64) {
#pragma unroll
        for (int i = 0; i < 4; i++) {   // stage A 128x64
            int id = i * 256 + tid;
            int r = id >> 3, b = id & 7;
            ushort8v v = (ushort8v)(unsigned short)0;
            int gr = m0 + r;
            if (gr < M) v = *(const ushort8v*)(A + (size_t)gr * lda + kk + b * 8);
            *(ushort8v*)(As + r * 64 + ((b ^ (r & 7)) * 8)) = v;
        }
#pragma unroll
        for (int i = 0; i < 4; i++) {   // stage B 128x64
            int id = i * 256 + tid;
            int r = id >> 3, b = id & 7;
            ushort8v v = (ushort8v)(unsigned short)0;
            int gr = n0 + r;
            if (gr < nRowsB) v = *(const ushort8v*)(Bt + (size_t)gr * ldb + kk + b * 8);
            *(ushort8v*)(Bs + r * 64 + ((b ^ (r & 7)) * 8)) = v;
        }
        __syncthreads();
#pragma unroll
        for (int ks = 0; ks < 2; ks++) {
            short8v af[4], bfv[4];
#pragma unroll
            for (int ti = 0; ti < 4; ti++) {
                int m = wr * 64 + ti * 16 + ln;
                int blk = (ks * 4 + q) ^ (m & 7);
                af[ti] = *(const short8v*)(As + m * 64 + blk * 8);
            }
#pragma unroll
            for (int tj = 0; tj < 4; tj++) {
                int n = wc * 64 + tj * 16 + ln;
                int blk = (ks * 4 + q) ^ (n & 7);
                bfv[tj] = *(const short8v*)(Bs + n * 64 + blk * 8);
            }
#pragma unroll
            for (int ti = 0; ti < 4; ti++)
#pragma unroll
                for (int tj = 0; tj < 4; tj++)
                    acc[ti][tj] = __builtin_amdgcn_mfma_f32_16x16x32_bf16(
                        af[ti], bfv[tj], acc[ti][tj], 0, 0, 0);
        }
        __syncthreads();
    }

#pragma unroll
    for (int ti = 0; ti < 4; ti++) {
        int rowb = m0 + wr * 64 + ti * 16 + q * 4;
#pragma unroll
        for (int tj = 0; tj < 4; tj++) {
            int col = n0 + wc * 64 + tj * 16 + ln;
            f32x4 c = acc[ti][tj];
            float bv = 0.f;
            if (!OUT_BF16 && bias) bv = bias[col];
#pragma unroll
            for (int r = 0; r < 4; r++) {
                int row = rowb + r;
                if (row < M) {
                    if (OUT_BF16)
                        ((unsigned short*)Cout)[(size_t)row * ldc + col] = f2bf(c[r]);
                    else
                        ((float*)Cout)[(size_t)row * ldc + col] = c[r] + bv;
                }
            }
        }
    }
}

// ---------------------------------------------------------------------------
// Fused gemm1 + bucket-scatter, interleaved by blockIdx&1 (disjoint pipes on
// every CU). u32 payloads (u16 stores cost ~16 us in the TCC pipe, round 7).
// cur doubles as the per-node count — no histogram, no scan.
// ---------------------------------------------------------------------------
__global__ __launch_bounds__(256) void gemm1_scatter(
    const unsigned short* __restrict__ X2feat, const unsigned short* __restrict__ W1t,
    unsigned short* __restrict__ AB,
    const int* __restrict__ src, const int* __restrict__ dst,
    int* __restrict__ cur, int* __restrict__ eSrc,
    int E, int gemmB, int N) {
    __shared__ unsigned short smem[2 * 128 * 64];
    int b = blockIdx.x;
    int half = b >> 1;
    if ((b & 1) == 0) {
        if (half >= gemmB) return;
        int m0 = (half >> 1) * 128, n0 = (half & 1) * 128;
        gemm_tile<true>(smem, smem + 128 * 64, X2feat, 256, W1t, 128, 256,
                        (void*)AB, 256, nullptr, N, 128, m0, n0);
    } else {
        int e = (half * 256 + threadIdx.x) * 4;
        if (e + 3 < E) {
            int4 s4 = *(const int4*)(src + e);
            int4 d4 = *(const int4*)(dst + e);
            int p0 = atomicAdd(&cur[d4.x], 1);
            int p1 = atomicAdd(&cur[d4.y], 1);
            int p2 = atomicAdd(&cur[d4.z], 1);
            int p3 = atomicAdd(&cur[d4.w], 1);
            eSrc[(size_t)d4.x * CAP + min(p0, CAP - 1)] = s4.x;
            eSrc[(size_t)d4.y * CAP + min(p1, CAP - 1)] = s4.y;
            eSrc[(size_t)d4.z * CAP + min(p2, CAP - 1)] = s4.z;
            eSrc[(size_t)d4.w * CAP + min(p3, CAP - 1)] = s4.w;
        } else {
            for (int i = e; i < E && i >= 0; i++) {
                int d = dst[i];
                int pos = atomicAdd(&cur[d], 1);
                eSrc[(size_t)d * CAP + min(pos, CAP - 1)] = src[i];
            }
        }
    }
}

// ---------------------------------------------------------------------------
// Gather: ONE WAVE PER NODE (12500 blocks -> full TLP for latency hiding;
// the round-8 fusion collapsed this to 1.5 blocks/CU and lost 45 us).
// 2 edges/step (half-wave each), ushort4 loads. Writes X2 cols 0..127 bf16.
// ---------------------------------------------------------------------------
__global__ __launch_bounds__(256) void gather_kernel(
    const unsigned short* __restrict__ AB, const int* __restrict__ cur,
    const int* __restrict__ eSrc,
    unsigned short* __restrict__ X2, int N) {
    int wid = (blockIdx.x * 256 + threadIdx.x) >> 6;
    int lane = threadIdx.x & 63;
    if (wid >= N) return;
    int num = min(cur[wid], CAP);
    size_t start = (size_t)wid * CAP;
    int half = lane >> 5, ln32 = lane & 31;
    ushort4 bv = *(const ushort4*)(AB + (size_t)wid * 256 + 128 + ln32 * 4);
    float b0 = bf2f(bv.x), b1 = bf2f(bv.y), b2 = bf2f(bv.z), b3 = bf2f(bv.w);
    float p0 = 0.f, p1 = 0.f, p2 = 0.f, p3 = 0.f;

    int mySrc = (lane < num) ? eSrc[start + lane] : 0;
    int j = 0;
    for (; j + 8 <= num; j += 8) {
        ushort4 v[4];
#pragma unroll
        for (int u = 0; u < 4; u++) {
            int s = __shfl(mySrc, j + 2 * u + half);
            v[u] = *(const ushort4*)(AB + (size_t)s * 256 + ln32 * 4);
        }
#pragma unroll
        for (int u = 0; u < 4; u++) {
            p0 += fmaxf(bf2f(v[u].x) + b0, 0.f);
            p1 += fmaxf(bf2f(v[u].y) + b1, 0.f);
            p2 += fmaxf(bf2f(v[u].z) + b2, 0.f);
            p3 += fmaxf(bf2f(v[u].w) + b3, 0.f);
        }
    }
    for (; j < num; j += 2) {
        int idx = j + half;
        int s = __shfl(mySrc, idx);
        bool ok = idx < num;
        ushort4 v = *(const ushort4*)(AB + (size_t)s * 256 + ln32 * 4);
        float m = ok ? 1.f : 0.f;
        p0 += m * fmaxf(bf2f(v.x) + b0, 0.f);
        p1 += m * fmaxf(bf2f(v.y) + b1, 0.f);
        p2 += m * fmaxf(bf2f(v.z) + b2, 0.f);
        p3 += m * fmaxf(bf2f(v.w) + b3, 0.f);
    }
    p0 += __shfl_xor(p0, 32);
    p1 += __shfl_xor(p1, 32);
    p2 += __shfl_xor(p2, 32);
    p3 += __shfl_xor(p3, 32);
    if (half == 0) {
        *(ushort4*)(X2 + (size_t)wid * 256 + ln32 * 4) =
            make_ushort4(f2bf(p0), f2bf(p1), f2bf(p2), f2bf(p3));
    }
}

// ---------------------------------------------------------------------------
// Standalone GEMM kernel (gemm2), 32 KB LDS.
// ---------------------------------------------------------------------------
template <bool OUT_BF16>
__global__ __launch_bounds__(256) void gemm128(
    const unsigned short* __restrict__ A, int lda,
    const unsigned short* __restrict__ Bt, int ldb, int nRowsB,
    void* __restrict__ Cout, int ldc,
    const float* __restrict__ bias, int M, int K) {
    __shared__ unsigned short smem[2 * 128 * 64];
    gemm_tile<OUT_BF16>(smem, smem + 128 * 64, A, lda, Bt, ldb, nRowsB,
                        Cout, ldc, bias, M, K, blockIdx.x * 128, blockIdx.y * 128);
}

// ---------------------------------------------------------------------------
extern "C" void kernel_launch(void* const* d_in, const int* in_sizes, int n_in,
                              void* d_out, int out_size, void* d_ws, size_t ws_size,
                              hipStream_t stream) {
    const float* feat = (const float*)d_in[0];
    const int* src = (const int*)d_in[1];
    const int* dst = (const int*)d_in[2];
    const float* W1 = (const float*)d_in[3];
    const float* W2 = (const float*)d_in[4];
    const float* LW = (const float*)d_in[5];
    const float* bias = (const float*)d_in[6];
    float* out = (float*)d_out;

    const int N = in_sizes[0] / 128;  // 50000
    const int E = in_sizes[1];        // 800000

    char* ws = (char*)d_ws;
    unsigned short* X2 = (unsigned short*)ws;            // [N,256] bf16: 0-127=S', 128-255=feat
    size_t off_b = (size_t)N * 256 * 2;
    unsigned short* AB = (unsigned short*)(ws + off_b);  // [N,256] bf16: A | B
    off_b += (size_t)N * 256 * 2;
    unsigned short* W1t = (unsigned short*)(ws + off_b);
    off_b += (size_t)256 * 128 * 2;
    unsigned short* W3t = (unsigned short*)(ws + off_b);
    off_b += (size_t)128 * 256 * 2;
    int* cur = (int*)(ws + off_b);   off_b += (size_t)N * 4;
    int* eSrc = (int*)(ws + off_b);  off_b += (size_t)N * CAP * 4;  // 12.8 MB

    int totalF = N * 128;
    int cvtB = (totalF / 4 + 255) / 256;

    hipMemsetAsync(cur, 0, (size_t)N * 4, stream);
    fused_pre<<<cvtB + 256, 256, 0, stream>>>(
        feat, X2, totalF, W1, W2, LW, W1t, W3t, cvtB);

    int gemmB = ((N + 127) / 128) * 2;     // 782 gemm tiles
    int scatB = ((E + 3) / 4 + 255) / 256; // 782 scatter chunks
    int mx = gemmB > scatB ? gemmB : scatB;
    gemm1_scatter<<<2 * mx, 256, 0, stream>>>(
        X2 + 128, W1t, AB, src, dst, cur, eSrc, E, gemmB, N);

    gather_kernel<<<(N + 3) / 4, 256, 0, stream>>>(AB, cur, eSrc, X2, N);

    dim3 g2((N + 127) / 128, 1);
    gemm128<false><<<g2, 256, 0, stream>>>(X2, 256, W3t, 256, 128,
                                           (void*)out, 128, bias, N, 256);
}